// Round 10
// baseline (9875.095 us; speedup 1.0000x reference)
//
#include <hip/hip_runtime.h>
#include <hip/hip_fp16.h>
#include <cstddef>

#define T_LEN 4096
#define HID 150
#define G4 600
#define NC 300

typedef __attribute__((ext_vector_type(8))) short bf16x8;      // 8 bf16 = 4 VGPRs
typedef __attribute__((ext_vector_type(8))) _Float16 f16x8;    // 8 fp16 = 4 VGPRs
typedef __attribute__((ext_vector_type(4))) float f32x4;

// raw barrier: waits LDS ops only, leaves global loads/stores in flight
__device__ __forceinline__ void barrier_lgkm() {
  asm volatile("s_waitcnt lgkmcnt(0)\n\ts_barrier" ::: "memory");
}

__device__ __forceinline__ float fsig(float x) {
  return __builtin_amdgcn_rcpf(1.f + __expf(-x));
}
__device__ __forceinline__ unsigned short f2bf(float f) {  // RNE fp32->bf16
  unsigned u = __builtin_bit_cast(unsigned, f);
  u += 0x7fff + ((u >> 16) & 1);
  return (unsigned short)(u >> 16);
}

// ---------------- LSTM scan via MFMA, activation-offloaded ---------------------
// r3 MFMA core (best measured); the gate ACTIVATIONS now run in the scatter
// waves (lanes 0-15 of all 8 waves, overlapping the 970-cyc MFMA pipe) using
// one sigmoid per value: tanh(x) = 2*sig(2x)-1 -> act = m*sig(m*g) - b with
// per-row (m,b). Activated values land in LDS channel-major g4[ch*4+gate], so
// the combine phase is one ds_read_b128 + c-update + one tanh. xg prefetch
// moved to scatter lanes (issued one step ahead -> full-step latency hiding).
__global__ __launch_bounds__(512, 2) void lstm_scan(
    const float* __restrict__ whh_solv, const float* __restrict__ whh_solu,
    const float* __restrict__ xg_base,
    float* __restrict__ o32v, float* __restrict__ o32u,
    __half* __restrict__ o16v, __half* __restrict__ o16u, int layer, int w32)
{
  __shared__ __align__(16) unsigned short h_bf[160];  // bf16 h, zeros beyond 150
  __shared__ __align__(16) float g4[704];  // [channel][gate]; 640.. = dump for pad rows
  const int c = blockIdx.x;
  const int net = c >> 1, dir = c & 1;
  const float* Whh = (net ? whh_solu : whh_solv) + (size_t)(layer * 2 + dir) * (G4 * HID);
  const float* xg = xg_base + (size_t)c * T_LEN * G4;
  float* out32 = (net ? o32u : o32v) + dir * HID;     // row stride NC (if w32)
  __half* out16 = (net ? o16u : o16v) + dir * HID;    // row stride 320
  const int tid = threadIdx.x;
  const int lane = tid & 63, wv = tid >> 6;
  const int lrow = lane & 15, lq = lane >> 4;  // frag row & k-quad

  // B-fragments: B[k][n] = Whh[n][k]; lane holds n=16*tile+lrow, k=kk*32+lq*8+i
  bf16x8 bfr[5][5];  // [j][kk]
#pragma unroll
  for (int j = 0; j < 5; j++) {
    const int jrow = 16 * (wv + 8 * j) + lrow;
#pragma unroll
    for (int kk = 0; kk < 5; kk++) {
      bf16x8 b;
#pragma unroll
      for (int i = 0; i < 8; i++) {
        const int k = kk * 32 + lq * 8 + i;
        const float v = (jrow < G4 && k < HID) ? Whh[(size_t)jrow * HID + k] : 0.f;
        b[i] = (short)f2bf(v);
      }
      bfr[j][kk] = b;
    }
  }

  // scatter-lane row metadata (meaningful for lane<16)
  int rj[5], idx[5];
  float mj[5], bj[5];
#pragma unroll
  for (int j = 0; j < 5; j++) {
    const int r = 16 * (wv + 8 * j) + lane;
    rj[j] = r;
    const int g = r / HID;            // 0..3 gate; 4 for pad rows >= 600
    const int ch = r - g * HID;
    const bool ist = (g == 2);        // gate order i,f,g,o: idx 2 is tanh
    idx[j] = (r < G4) ? (ch * 4 + g) : (640 + (r - G4));
    mj[j] = ist ? 2.f : 1.f;
    bj[j] = ist ? 1.f : 0.f;
  }

  if (tid < 160) h_bf[tid] = 0;
  float cst = 0.f;
  float xn[5] = {0.f, 0.f, 0.f, 0.f, 0.f};  // next-step xg for owned rows
  if (lane < 16) {
    const int t0 = dir ? (T_LEN - 1) : 0;
    const float* b = xg + (size_t)t0 * G4;
#pragma unroll
    for (int j = 0; j < 5; j++) xn[j] = (rj[j] < G4) ? b[rj[j]] : 0.f;
  }
  const f32x4 z4 = {0.f, 0.f, 0.f, 0.f};
  barrier_lgkm();

  for (int s = 0; s < T_LEN; s++) {
    const int t = dir ? (T_LEN - 1 - s) : s;
    float xq[5];
    if (lane < 16) {
#pragma unroll
      for (int j = 0; j < 5; j++) xq[j] = xn[j];   // vmcnt wait (loads from s-1)
      if (s + 1 < T_LEN) {                          // issue next-step loads NOW
        const int tn = dir ? (T_LEN - 2 - s) : (s + 1);
        const float* b = xg + (size_t)tn * G4;
#pragma unroll
        for (int j = 0; j < 5; j++) xn[j] = (rj[j] < G4) ? b[rj[j]] : 0.f;
      }
    }
    // A-frags: row0 = h_bf, rows 1-15 zero
    bf16x8 af[5];
#pragma unroll
    for (int kk = 0; kk < 5; kk++) {
      bf16x8 a = {0, 0, 0, 0, 0, 0, 0, 0};
      if (lrow == 0) a = *(const bf16x8*)&h_bf[kk * 32 + lq * 8];
      af[kk] = a;
    }
    f32x4 acc[5];
#pragma unroll
    for (int j = 0; j < 5; j++)
      acc[j] = __builtin_amdgcn_mfma_f32_16x16x32_bf16(af[0], bfr[j][0], z4, 0, 0, 0);
#pragma unroll
    for (int kk = 1; kk < 5; kk++)
#pragma unroll
      for (int j = 0; j < 5; j++)
        acc[j] = __builtin_amdgcn_mfma_f32_16x16x32_bf16(af[kk], bfr[j][kk], acc[j], 0, 0, 0);
    // scatter WITH activation: act = m*sig(m*g) - b  (sig for i/f/o, tanh for g)
    if (lane < 16) {
#pragma unroll
      for (int j = 0; j < 5; j++) {
        const float g = xq[j] + acc[j][0];
        g4[idx[j]] = mj[j] * fsig(mj[j] * g) - bj[j];
      }
    }
    barrier_lgkm();
    if (tid < HID) {
      const float4 a = *(const float4*)&g4[tid * 4];  // i,f,g,o activated
      cst = a.y * cst + a.x * a.z;
      const float th = 2.f * fsig(2.f * cst) - 1.f;
      const float hv = a.w * th;
      h_bf[tid] = f2bf(hv);
      out16[(size_t)t * 320 + tid] = __float2half(hv);
      if (w32) out32[(size_t)t * NC + tid] = hv;
    }
    barrier_lgkm();
  }
}

// ---------------- fp32 -> fp16 conversion helpers ------------------------------
// Wihh[8][640][320]: slot s = l*4 + net*2 + dir, zero-padded rows/cols
__global__ void conv_w(const float* __restrict__ wv, const float* __restrict__ wu,
                       __half* __restrict__ dst)
{
  const int gid = blockIdx.x * 256 + threadIdx.x;
  if (gid >= 8 * 640 * 320) return;
  const int k = gid % 320, j = (gid / 320) % 640, s = gid / (320 * 640);
  const int l = s >> 2, net = (s >> 1) & 1, dir = s & 1;
  float v = 0.f;
  if (j < G4 && k < NC) {
    const float* src = (net ? wu : wv) + (size_t)(l * 2 + dir) * (G4 * NC);
    v = src[(size_t)j * NC + k];
  }
  dst[gid] = __float2half(v);
}

// X fp32 [rows][300] -> Xh fp16 [rows][320] zero-padded
__global__ void conv_x(const float* __restrict__ src, __half* __restrict__ dst, int rows)
{
  const int gid = blockIdx.x * 256 + threadIdx.x;
  if (gid >= rows * 320) return;
  const int k = gid % 320, m = gid / 320;
  dst[gid] = __float2half(k < NC ? src[(size_t)m * NC + k] : 0.f);
}

// X fp32 [4096][300] -> XT fp16 [320][4096] (rows >= 300 zeroed)
__global__ void conv_t(const float* __restrict__ src, __half* __restrict__ dst)
{
  const int gid = blockIdx.x * 256 + threadIdx.x;
  if (gid >= 320 * 4096) return;
  const int m = gid % 4096, f = gid / 4096;
  dst[gid] = __float2half(f < NC ? src[(size_t)m * NC + f] : 0.f);
}

__global__ void zero_f(float* __restrict__ p, int n) {
  const int i = blockIdx.x * 256 + threadIdx.x;
  if (i < n) p[i] = 0.f;
}

// ---------------- xg = X @ Wih^T + b via fp16 MFMA -----------------------------
// grid (64 m-blocks, 4 chains), block 256 (4 waves, 16 rows each). N=640, K=320.
__global__ __launch_bounds__(256) void xg_mfma(
    const __half* __restrict__ Av, const __half* __restrict__ Au,
    const __half* __restrict__ W,   // Wihh + layer*4*640*320
    const float* __restrict__ bihv, const float* __restrict__ bhhv,
    const float* __restrict__ bihu, const float* __restrict__ bhhu,
    float* __restrict__ xg, int layer)
{
  const int tid = threadIdx.x;
  const int lane = tid & 63, wv = tid >> 6;
  const int ln = lane & 15, q = lane >> 4;
  const int chain = blockIdx.y;
  const __half* A = (chain >= 2) ? Au : Av;
  const __half* Wc = W + (size_t)chain * 640 * 320;
  const float* bi = ((chain >= 2) ? bihu : bihv) + (size_t)(layer * 2 + (chain & 1)) * G4;
  const float* bh = ((chain >= 2) ? bhhu : bhhv) + (size_t)(layer * 2 + (chain & 1)) * G4;
  float* C = xg + (size_t)chain * T_LEN * G4;
  const int m0 = blockIdx.x * 64 + wv * 16;
  const __half* Arow = A + (size_t)(m0 + ln) * 320;

  for (int nc = 0; nc < 4; nc++) {       // 4 chunks x 160 cols
    f32x4 acc[10];
#pragma unroll
    for (int j = 0; j < 10; j++) acc[j] = (f32x4){0.f, 0.f, 0.f, 0.f};
    for (int kk = 0; kk < 10; kk++) {
      const f16x8 afr = *(const f16x8*)(Arow + kk * 32 + q * 8);
#pragma unroll
      for (int j = 0; j < 10; j++) {
        const int n = nc * 160 + j * 16 + ln;
        const f16x8 bfr = *(const f16x8*)(Wc + (size_t)n * 320 + kk * 32 + q * 8);
        acc[j] = __builtin_amdgcn_mfma_f32_16x16x32_f16(afr, bfr, acc[j], 0, 0, 0);
      }
    }
#pragma unroll
    for (int j = 0; j < 10; j++) {
      const int n = nc * 160 + j * 16 + ln;
      if (n < G4) {
        const float bias = bi[n] + bh[n];
#pragma unroll
        for (int r = 0; r < 4; r++)
          C[(size_t)(m0 + q * 4 + r) * G4 + n] = acc[j][r] + bias;
      }
    }
  }
}

// ------- S GEMM: AH[m][n] = fp16(Hh[m] . Gh[n]), raw scores (no exp) -----------
__global__ __launch_bounds__(256) void s_gemm(
    const __half* __restrict__ Hh, const __half* __restrict__ Gh,
    __half* __restrict__ AH)
{
  const int tid = threadIdx.x;
  const int lane = tid & 63, wv = tid >> 6;
  const int ln = lane & 15, q = lane >> 4;
  const int m0 = blockIdx.x * 64 + wv * 16;
  const __half* Arow = Hh + (size_t)(m0 + ln) * 320;
  f16x8 afr[10];
#pragma unroll
  for (int kk = 0; kk < 10; kk++) afr[kk] = *(const f16x8*)(Arow + kk * 32 + q * 8);
  const int nt0 = blockIdx.y * 64;
  for (int nt = 0; nt < 64; nt++) {
    const int n = 16 * (nt0 + nt) + ln;
    const __half* Brow = Gh + (size_t)n * 320;
    f32x4 acc = (f32x4){0.f, 0.f, 0.f, 0.f};
#pragma unroll
    for (int kk = 0; kk < 10; kk++) {
      const f16x8 bfr = *(const f16x8*)(Brow + kk * 32 + q * 8);
      acc = __builtin_amdgcn_mfma_f32_16x16x32_f16(afr[kk], bfr, acc, 0, 0, 0);
    }
#pragma unroll
    for (int r = 0; r < 4; r++)
      AH[(size_t)(m0 + q * 4 + r) * 4096 + n] = __float2half(acc[r]);
  }
}

// ------- rowsum: il[m] = 1 / sum_n exp(S[m][n] - 30)  (one block per row) ------
__global__ __launch_bounds__(256) void rowsum_k(const __half* __restrict__ AH,
                                                float* __restrict__ il)
{
  const int m = blockIdx.x, tid = threadIdx.x;
  const __half* row = AH + (size_t)m * 4096;
  float s = 0.f;
  for (int i = tid * 8; i < 4096; i += 2048) {
    const f16x8 v = *(const f16x8*)(row + i);
#pragma unroll
    for (int j = 0; j < 8; j++) s += __expf(fminf((float)v[j] - 30.f, 80.f));
  }
#pragma unroll
  for (int off = 32; off > 0; off >>= 1) s += __shfl_down(s, off);
  __shared__ float red[4];
  if ((tid & 63) == 0) red[tid >> 6] = s;
  __syncthreads();
  if (tid == 0) il[m] = 1.f / (red[0] + red[1] + red[2] + red[3]);
}

// ------- scale: AH = fp16( exp(S-30) * il[m] ), in place -----------------------
__global__ __launch_bounds__(256) void scale_k(__half* __restrict__ AH,
                                               const float* __restrict__ il)
{
  const size_t gid = (size_t)blockIdx.x * 256 + threadIdx.x;  // f16x8 chunk id
  const int m = (int)(gid >> 9);                              // 512 chunks/row
  const float ilm = il[m];
  f16x8 v = *(f16x8*)(AH + gid * 8);
#pragma unroll
  for (int j = 0; j < 8; j++)
    v[j] = (_Float16)(__expf(fminf((float)v[j] - 30.f, 80.f)) * ilm);
  *(f16x8*)(AH + gid * 8) = v;
}

// ------- P = AH @ GhT' and Q = AH^T @ HhT' in ONE dispatch (128 blocks) --------
__global__ __launch_bounds__(256) void pq_mfma(
    const __half* __restrict__ AH, const __half* __restrict__ GhT,
    const __half* __restrict__ HhT,
    float* __restrict__ Pb, float* __restrict__ Qb)
{
  __shared__ __align__(16) _Float16 Ats[64][72];  // qt staging, pitch 144 B
  const int tid = threadIdx.x;
  const int lane = tid & 63, wv = tid >> 6;
  const int ln = lane & 15, q = lane >> 4;

  if (blockIdx.x < 64) {
    // ---- P part: M=4096 rows of AH, N=320(store 300), K=4096 ----
    const int m0 = blockIdx.x * 64 + wv * 16;
    const __half* Arow = AH + (size_t)(m0 + ln) * 4096;
    for (int nc = 0; nc < 2; nc++) {
      f32x4 acc[10];
#pragma unroll
      for (int j = 0; j < 10; j++) acc[j] = (f32x4){0.f, 0.f, 0.f, 0.f};
      for (int kk = 0; kk < 128; kk++) {
        const f16x8 afr = *(const f16x8*)(Arow + kk * 32 + q * 8);
#pragma unroll
        for (int j = 0; j < 10; j++) {
          const int n = nc * 160 + j * 16 + ln;
          const f16x8 bfr = *(const f16x8*)(GhT + (size_t)n * 4096 + kk * 32 + q * 8);
          acc[j] = __builtin_amdgcn_mfma_f32_16x16x32_f16(afr, bfr, acc[j], 0, 0, 0);
        }
      }
#pragma unroll
      for (int j = 0; j < 10; j++) {
        const int n = nc * 160 + j * 16 + ln;
        if (n < NC) {
#pragma unroll
          for (int r = 0; r < 4; r++)
            Pb[(size_t)(m0 + q * 4 + r) * NC + n] = acc[j][r];
        }
      }
    }
  } else {
    // ---- Q part: Q[j][f] = sum_i a[i][j] H[i][f]; a transposed via LDS ----
    const int j0 = (blockIdx.x - 64) * 64;
    f32x4 acc[20];
#pragma unroll
    for (int j = 0; j < 20; j++) acc[j] = (f32x4){0.f, 0.f, 0.f, 0.f};
    const int il8 = tid >> 2, j8 = (tid & 3) * 16;  // staging role
    for (int ic = 0; ic < 4096; ic += 64) {
      __syncthreads();
      {
        const __half* src = AH + (size_t)(ic + il8) * 4096 + j0 + j8;
        const f16x8 v0 = *(const f16x8*)src;
        const f16x8 v1 = *(const f16x8*)(src + 8);
#pragma unroll
        for (int jj = 0; jj < 8; jj++) Ats[j8 + jj][il8] = v0[jj];
#pragma unroll
        for (int jj = 0; jj < 8; jj++) Ats[j8 + 8 + jj][il8] = v1[jj];
      }
      __syncthreads();
#pragma unroll
      for (int s = 0; s < 2; s++) {
        const f16x8 afr = *(const f16x8*)&Ats[wv * 16 + ln][s * 32 + q * 8];
        const __half* bbase = HhT + ic + s * 32 + q * 8;
#pragma unroll
        for (int j = 0; j < 20; j++) {
          const f16x8 bfr = *(const f16x8*)(bbase + (size_t)(j * 16 + ln) * 4096);
          acc[j] = __builtin_amdgcn_mfma_f32_16x16x32_f16(afr, bfr, acc[j], 0, 0, 0);
        }
      }
    }
#pragma unroll
    for (int j = 0; j < 20; j++) {
      const int f = j * 16 + ln;
      if (f < NC) {
#pragma unroll
        for (int r = 0; r < 4; r++)
          Qb[(size_t)(j0 + wv * 16 + q * 4 + r) * NC + f] = acc[j][r];
      }
    }
  }
}

// ---------------- tail ---------------------------------------------------------
__global__ void reduce_uv(const float* __restrict__ X, const float* __restrict__ Yp,
                          float* __restrict__ inp, int off)
{
  const int j = threadIdx.x;
  if (j >= NC) return;
  const int r0 = blockIdx.x * 128;
  float s = 0.f;
  for (int r = r0; r < r0 + 128; r++)
    s += fmaxf(X[(size_t)r * NC + j], Yp[(size_t)r * NC + j]);
  atomicAdd(&inp[off + j], s);
}

__global__ void fc1_k(const float* __restrict__ w1, const float* __restrict__ b1,
                      const float* __restrict__ inp, float* __restrict__ x)
{
  const int r = blockIdx.x * 256 + threadIdx.x;
  if (r >= 2000) return;
  float s = b1[r];
  const float* wr = w1 + (size_t)r * 600;
  for (int k = 0; k < 600; k++) s += wr[k] * inp[k];
  x[r] = fmaxf(s, 0.f);
}

__global__ void fc2_k(const float* __restrict__ x, const float* __restrict__ w2,
                      const float* __restrict__ b2, float* __restrict__ outp)
{
  const int tid = threadIdx.x;
  float s = 0.f;
  for (int i = tid; i < 2000; i += 256) s += x[i] * w2[i];
#pragma unroll
  for (int off = 32; off > 0; off >>= 1) s += __shfl_down(s, off);
  __shared__ float red[4];
  if ((tid & 63) == 0) red[tid >> 6] = s;
  __syncthreads();
  if (tid == 0) outp[0] = red[0] + red[1] + red[2] + red[3] + b2[0];
}

// ---------------- launch --------------------------------------------------------
extern "C" void kernel_launch(void* const* d_in, const int* in_sizes, int n_in,
                              void* d_out, int out_size, void* d_ws, size_t ws_size,
                              hipStream_t stream)
{
  const float* in_solv  = (const float*)d_in[0];
  const float* in_solu  = (const float*)d_in[1];
  const float* solv_Wih = (const float*)d_in[2];
  const float* solv_Whh = (const float*)d_in[3];
  const float* solv_bih = (const float*)d_in[4];
  const float* solv_bhh = (const float*)d_in[5];
  const float* solu_Wih = (const float*)d_in[6];
  const float* solu_Whh = (const float*)d_in[7];
  const float* solu_bih = (const float*)d_in[8];
  const float* solu_bhh = (const float*)d_in[9];
  const float* fc1_w = (const float*)d_in[10];
  const float* fc1_b = (const float*)d_in[11];
  const float* fc2_w = (const float*)d_in[12];
  const float* fc2_b = (const float*)d_in[13];
  float* outp = (float*)d_out;
  float* ws = (float*)d_ws;

  // ---- workspace layout (float offsets); peak 16,067,200 fl ----
  constexpr size_t off_P   = 0;
  constexpr size_t off_Q   = 1228800;
  constexpr size_t off_inp = 2457600;   // 640
  constexpr size_t off_x   = 2458240;   // 2048
  constexpr size_t off_il  = 2460288;   // 4096
  constexpr size_t off_xg  = 2468480;
  constexpr size_t off_L0  = off_xg + (size_t)4 * 2457600;   // 12,298,880
  constexpr size_t off_HG  = off_L0 + 1310720;               // 13,609,600

  float*  xg   = ws + off_xg;
  float*  Hb   = ws + off_HG;
  float*  Gb   = Hb + 1228800;
  float*  Pb   = ws + off_P;
  float*  Qb   = ws + off_Q;
  float*  inp  = ws + off_inp;
  float*  xf   = ws + off_x;
  float*  il   = ws + off_il;
  __half* Wihh = (__half*)(ws + off_P);
  __half* Avh  = (__half*)(ws + off_L0);
  __half* Auh  = Avh + 4096 * 320;
  __half* L0vh = (__half*)(ws + off_HG);
  __half* L0uh = L0vh + 4096 * 320;
  __half* Hh   = (__half*)(ws + off_L0);   // reuses Avh/Auh space (dead)
  __half* Gh   = Hh + 4096 * 320;
  __half* AH   = (__half*)(ws + off_xg);   // after scans (xg dead)
  __half* HhT  = AH + (size_t)4096 * 4096;
  __half* GhT  = HhT + 320 * 4096;

  // ---- prep: zero L0vh/L0uh pads, convert weights + inputs to fp16 ----
  zero_f<<<5120, 256, 0, stream>>>(ws + off_HG, 1310720);
  conv_w<<<(8 * 640 * 320 + 255) / 256, 256, 0, stream>>>(solv_Wih, solu_Wih, Wihh);
  conv_x<<<5120, 256, 0, stream>>>(in_solv, Avh, 4096);
  conv_x<<<5120, 256, 0, stream>>>(in_solu, Auh, 4096);

  // ---- layer 0 (scan writes fp16 L0vh/L0uh directly; no fp32 out) ----
  xg_mfma<<<dim3(64, 4), 256, 0, stream>>>(Avh, Auh, Wihh,
      solv_bih, solv_bhh, solu_bih, solu_bhh, xg, 0);
  lstm_scan<<<4, 512, 0, stream>>>(solv_Whh, solu_Whh, xg,
      nullptr, nullptr, L0vh, L0uh, 0, 0);

  // ---- layer 1 (scan writes fp32 Hb/Gb + fp16 Hh/Gh) ----
  xg_mfma<<<dim3(64, 4), 256, 0, stream>>>(L0vh, L0uh, Wihh + (size_t)4 * 640 * 320,
      solv_bih, solv_bhh, solu_bih, solu_bhh, xg, 1);
  lstm_scan<<<4, 512, 0, stream>>>(solv_Whh, solu_Whh, xg,
      Hb, Gb, Hh, Gh, 1, 1);

  // ---- attention: S once (fp16), rowsum, scale, P/Q combined ----
  conv_t<<<5120, 256, 0, stream>>>(Hb, HhT);
  conv_t<<<5120, 256, 0, stream>>>(Gb, GhT);
  s_gemm<<<dim3(64, 4), 256, 0, stream>>>(Hh, Gh, AH);
  rowsum_k<<<4096, 256, 0, stream>>>(AH, il);
  scale_k<<<8192, 256, 0, stream>>>(AH, il);
  pq_mfma<<<128, 256, 0, stream>>>(AH, GhT, HhT, Pb, Qb);

  // ---- tail ----
  zero_f<<<3, 256, 0, stream>>>(inp, 640);
  reduce_uv<<<32, 320, 0, stream>>>(Hb, Pb, inp, 0);
  reduce_uv<<<32, 320, 0, stream>>>(Gb, Qb, inp, 300);
  fc1_k<<<8, 256, 0, stream>>>(fc1_w, fc1_b, inp, xf);
  fc2_k<<<1, 256, 0, stream>>>(xf, fc2_w, fc2_b, outp);
}

// Round 11
// 7066.348 us; speedup vs baseline: 1.3975x; 1.3975x over previous
//
#include <hip/hip_runtime.h>
#include <hip/hip_fp16.h>
#include <cstddef>

#define T_LEN 4096
#define HID 150
#define G4 600
#define NC 300

typedef __attribute__((ext_vector_type(8))) short bf16x8;      // 8 bf16 = 4 VGPRs
typedef __attribute__((ext_vector_type(8))) _Float16 f16x8;    // 8 fp16 = 4 VGPRs
typedef __attribute__((ext_vector_type(4))) float f32x4;

// raw barrier: waits LDS ops only, leaves global loads/stores in flight
__device__ __forceinline__ void barrier_lgkm() {
  asm volatile("s_waitcnt lgkmcnt(0)\n\ts_barrier" ::: "memory");
}

__device__ __forceinline__ float fsig(float x) {
  return __builtin_amdgcn_rcpf(1.f + __expf(-x));
}
__device__ __forceinline__ float ftanh(float x) {
  float ax = fabsf(x);
  float e = __expf(2.f * ax);
  float t = 1.f - 2.f * __builtin_amdgcn_rcpf(e + 1.f);
  return copysignf(t, x);
}
__device__ __forceinline__ unsigned short f2bf(float f) {  // RNE fp32->bf16
  unsigned u = __builtin_bit_cast(unsigned, f);
  u += 0x7fff + ((u >> 16) & 1);
  return (unsigned short)(u >> 16);
}

// ---------------- LSTM scan via MFMA: EXACT r3/r9 structure (best measured) ----
// 1812 cyc/step incl fused fp16 store. 4 chains, one block (8 waves).
// g[640] = h[160] @ WhhT as 16x16x32 bf16 MFMA, A row0 = h, rows 1-15 = 0.
// DO NOT restructure. Measured ladder (cyc/step): r3/r9 1743/1812 < r5 af-hoist
// 1854 < r8 1-barrier 1893 < r7 16-wave 1968 < r6 gate-permute 2439 <
// r10 act-offload 2651 (bank conflicts + lengthened pre-barrier path).
__global__ __launch_bounds__(512, 2) void lstm_scan(
    const float* __restrict__ whh_solv, const float* __restrict__ whh_solu,
    const float* __restrict__ xg_base,
    float* __restrict__ o32v, float* __restrict__ o32u,
    __half* __restrict__ o16v, __half* __restrict__ o16u, int layer, int w32)
{
  __shared__ __align__(16) unsigned short h_bf[160];  // bf16 h, zeros beyond 150
  __shared__ float g_s[640];
  const int c = blockIdx.x;
  const int net = c >> 1, dir = c & 1;
  const float* Whh = (net ? whh_solu : whh_solv) + (size_t)(layer * 2 + dir) * (G4 * HID);
  const float* xg = xg_base + (size_t)c * T_LEN * G4;
  float* out32 = (net ? o32u : o32v) + dir * HID;     // row stride NC (if w32)
  __half* out16 = (net ? o16u : o16v) + dir * HID;    // row stride 320
  const int tid = threadIdx.x;
  const int lane = tid & 63, wv = tid >> 6;
  const int lrow = lane & 15, lq = lane >> 4;  // frag row & k-quad

  // B-fragments: B[k][n] = Whh[n][k]; lane holds n=16*tile+lrow, k=kk*32+lq*8+i
  bf16x8 bfr[5][5];  // [j][kk]
#pragma unroll
  for (int j = 0; j < 5; j++) {
    const int jrow = 16 * (wv + 8 * j) + lrow;
#pragma unroll
    for (int kk = 0; kk < 5; kk++) {
      bf16x8 b;
#pragma unroll
      for (int i = 0; i < 8; i++) {
        const int k = kk * 32 + lq * 8 + i;
        const float v = (jrow < G4 && k < HID) ? Whh[(size_t)jrow * HID + k] : 0.f;
        b[i] = (short)f2bf(v);
      }
      bfr[j][kk] = b;
    }
  }
  if (tid < 160) h_bf[tid] = 0;
  float cst = 0.f;
  float xr0 = 0.f, xr1 = 0.f, xr2 = 0.f, xr3 = 0.f;
  if (tid < HID) {
    const int t0 = dir ? (T_LEN - 1) : 0;
    const float* xgr = xg + (size_t)t0 * G4 + tid;
    xr0 = xgr[0]; xr1 = xgr[HID]; xr2 = xgr[2 * HID]; xr3 = xgr[3 * HID];
  }
  barrier_lgkm();

  for (int s = 0; s < T_LEN; s++) {
    const int t = dir ? (T_LEN - 1 - s) : s;
    // A-frags: row0 = h_bf, rows 1-15 zero -> only lanes with lrow==0 load
    bf16x8 af[5];
#pragma unroll
    for (int kk = 0; kk < 5; kk++) {
      bf16x8 a = {0, 0, 0, 0, 0, 0, 0, 0};
      if (lrow == 0) a = *(const bf16x8*)&h_bf[kk * 32 + lq * 8];
      af[kk] = a;
    }
    f32x4 acc[5];
#pragma unroll
    for (int j = 0; j < 5; j++) acc[j] = (f32x4){0.f, 0.f, 0.f, 0.f};
#pragma unroll
    for (int kk = 0; kk < 5; kk++)
#pragma unroll
      for (int j = 0; j < 5; j++)
        acc[j] = __builtin_amdgcn_mfma_f32_16x16x32_bf16(af[kk], bfr[j][kk], acc[j], 0, 0, 0);
    // D row0 lives in lanes 0-15, reg 0
    if (lane < 16) {
#pragma unroll
      for (int j = 0; j < 5; j++) g_s[16 * (wv + 8 * j) + lane] = acc[j][0];
    }
    barrier_lgkm();
    if (tid < HID) {
      const int n = tid;
      float gi = xr0 + g_s[n];
      float gf = xr1 + g_s[HID + n];
      float gg = xr2 + g_s[2 * HID + n];
      float go = xr3 + g_s[3 * HID + n];
      if (s + 1 < T_LEN) {  // prefetch next xg row (stays in flight past barrier)
        const int tn = dir ? (T_LEN - 2 - s) : (s + 1);
        const float* xgr = xg + (size_t)tn * G4 + n;
        xr0 = xgr[0]; xr1 = xgr[HID]; xr2 = xgr[2 * HID]; xr3 = xgr[3 * HID];
      }
      const float iv = fsig(gi), fv = fsig(gf), gv = ftanh(gg), ov = fsig(go);
      cst = fv * cst + iv * gv;
      const float hv = ov * ftanh(cst);
      h_bf[n] = f2bf(hv);      // matvec input rounded; c/h state stays fp32
      out16[(size_t)t * 320 + n] = __float2half(hv);
      if (w32) out32[(size_t)t * NC + n] = hv;
    }
    barrier_lgkm();
  }
}

// ---------------- fp32 -> fp16 conversion helpers ------------------------------
// Wihh[8][640][320]: slot s = l*4 + net*2 + dir, zero-padded rows/cols
__global__ void conv_w(const float* __restrict__ wv, const float* __restrict__ wu,
                       __half* __restrict__ dst)
{
  const int gid = blockIdx.x * 256 + threadIdx.x;
  if (gid >= 8 * 640 * 320) return;
  const int k = gid % 320, j = (gid / 320) % 640, s = gid / (320 * 640);
  const int l = s >> 2, net = (s >> 1) & 1, dir = s & 1;
  float v = 0.f;
  if (j < G4 && k < NC) {
    const float* src = (net ? wu : wv) + (size_t)(l * 2 + dir) * (G4 * NC);
    v = src[(size_t)j * NC + k];
  }
  dst[gid] = __float2half(v);
}

// X fp32 [rows][300] -> Xh fp16 [rows][320] zero-padded
__global__ void conv_x(const float* __restrict__ src, __half* __restrict__ dst, int rows)
{
  const int gid = blockIdx.x * 256 + threadIdx.x;
  if (gid >= rows * 320) return;
  const int k = gid % 320, m = gid / 320;
  dst[gid] = __float2half(k < NC ? src[(size_t)m * NC + k] : 0.f);
}

// X fp32 [4096][300] -> XT fp16 [320][4096] (rows >= 300 zeroed)
__global__ void conv_t(const float* __restrict__ src, __half* __restrict__ dst)
{
  const int gid = blockIdx.x * 256 + threadIdx.x;
  if (gid >= 320 * 4096) return;
  const int m = gid % 4096, f = gid / 4096;
  dst[gid] = __float2half(f < NC ? src[(size_t)m * NC + f] : 0.f);
}

__global__ void zero_f(float* __restrict__ p, int n) {
  const int i = blockIdx.x * 256 + threadIdx.x;
  if (i < n) p[i] = 0.f;
}

// ---------------- xg = X @ Wih^T + b via fp16 MFMA -----------------------------
// grid (64 m-blocks, 4 chains), block 256 (4 waves, 16 rows each). N=640, K=320.
__global__ __launch_bounds__(256) void xg_mfma(
    const __half* __restrict__ Av, const __half* __restrict__ Au,
    const __half* __restrict__ W,   // Wihh + layer*4*640*320
    const float* __restrict__ bihv, const float* __restrict__ bhhv,
    const float* __restrict__ bihu, const float* __restrict__ bhhu,
    float* __restrict__ xg, int layer)
{
  const int tid = threadIdx.x;
  const int lane = tid & 63, wv = tid >> 6;
  const int ln = lane & 15, q = lane >> 4;
  const int chain = blockIdx.y;
  const __half* A = (chain >= 2) ? Au : Av;
  const __half* Wc = W + (size_t)chain * 640 * 320;
  const float* bi = ((chain >= 2) ? bihu : bihv) + (size_t)(layer * 2 + (chain & 1)) * G4;
  const float* bh = ((chain >= 2) ? bhhu : bhhv) + (size_t)(layer * 2 + (chain & 1)) * G4;
  float* C = xg + (size_t)chain * T_LEN * G4;
  const int m0 = blockIdx.x * 64 + wv * 16;
  const __half* Arow = A + (size_t)(m0 + ln) * 320;

  for (int nc = 0; nc < 4; nc++) {       // 4 chunks x 160 cols
    f32x4 acc[10];
#pragma unroll
    for (int j = 0; j < 10; j++) acc[j] = (f32x4){0.f, 0.f, 0.f, 0.f};
    for (int kk = 0; kk < 10; kk++) {
      const f16x8 afr = *(const f16x8*)(Arow + kk * 32 + q * 8);
#pragma unroll
      for (int j = 0; j < 10; j++) {
        const int n = nc * 160 + j * 16 + ln;
        const f16x8 bfr = *(const f16x8*)(Wc + (size_t)n * 320 + kk * 32 + q * 8);
        acc[j] = __builtin_amdgcn_mfma_f32_16x16x32_f16(afr, bfr, acc[j], 0, 0, 0);
      }
    }
#pragma unroll
    for (int j = 0; j < 10; j++) {
      const int n = nc * 160 + j * 16 + ln;
      if (n < G4) {
        const float bias = bi[n] + bh[n];
#pragma unroll
        for (int r = 0; r < 4; r++)
          C[(size_t)(m0 + q * 4 + r) * G4 + n] = acc[j][r] + bias;
      }
    }
  }
}

// ------- S GEMM: AH[m][n] = fp16(Hh[m] . Gh[n]), raw scores (no exp) -----------
__global__ __launch_bounds__(256) void s_gemm(
    const __half* __restrict__ Hh, const __half* __restrict__ Gh,
    __half* __restrict__ AH)
{
  const int tid = threadIdx.x;
  const int lane = tid & 63, wv = tid >> 6;
  const int ln = lane & 15, q = lane >> 4;
  const int m0 = blockIdx.x * 64 + wv * 16;
  const __half* Arow = Hh + (size_t)(m0 + ln) * 320;
  f16x8 afr[10];
#pragma unroll
  for (int kk = 0; kk < 10; kk++) afr[kk] = *(const f16x8*)(Arow + kk * 32 + q * 8);
  const int nt0 = blockIdx.y * 64;
  for (int nt = 0; nt < 64; nt++) {
    const int n = 16 * (nt0 + nt) + ln;
    const __half* Brow = Gh + (size_t)n * 320;
    f32x4 acc = (f32x4){0.f, 0.f, 0.f, 0.f};
#pragma unroll
    for (int kk = 0; kk < 10; kk++) {
      const f16x8 bfr = *(const f16x8*)(Brow + kk * 32 + q * 8);
      acc = __builtin_amdgcn_mfma_f32_16x16x32_f16(afr[kk], bfr, acc, 0, 0, 0);
    }
#pragma unroll
    for (int r = 0; r < 4; r++)
      AH[(size_t)(m0 + q * 4 + r) * 4096 + n] = __float2half(acc[r]);
  }
}

// ------- rowsum: il[m] = 1 / sum_n exp(S[m][n] - 30)  (one block per row) ------
__global__ __launch_bounds__(256) void rowsum_k(const __half* __restrict__ AH,
                                                float* __restrict__ il)
{
  const int m = blockIdx.x, tid = threadIdx.x;
  const __half* row = AH + (size_t)m * 4096;
  float s = 0.f;
  for (int i = tid * 8; i < 4096; i += 2048) {
    const f16x8 v = *(const f16x8*)(row + i);
#pragma unroll
    for (int j = 0; j < 8; j++) s += __expf(fminf((float)v[j] - 30.f, 80.f));
  }
#pragma unroll
  for (int off = 32; off > 0; off >>= 1) s += __shfl_down(s, off);
  __shared__ float red[4];
  if ((tid & 63) == 0) red[tid >> 6] = s;
  __syncthreads();
  if (tid == 0) il[m] = 1.f / (red[0] + red[1] + red[2] + red[3]);
}

// ------- scale: AH = fp16( exp(S-30) * il[m] ), in place -----------------------
__global__ __launch_bounds__(256) void scale_k(__half* __restrict__ AH,
                                               const float* __restrict__ il)
{
  const size_t gid = (size_t)blockIdx.x * 256 + threadIdx.x;  // f16x8 chunk id
  const int m = (int)(gid >> 9);                              // 512 chunks/row
  const float ilm = il[m];
  f16x8 v = *(f16x8*)(AH + gid * 8);
#pragma unroll
  for (int j = 0; j < 8; j++)
    v[j] = (_Float16)(__expf(fminf((float)v[j] - 30.f, 80.f)) * ilm);
  *(f16x8*)(AH + gid * 8) = v;
}

// ------- P = AH @ GhT' and Q = AH^T @ HhT' in ONE dispatch (128 blocks) --------
__global__ __launch_bounds__(256) void pq_mfma(
    const __half* __restrict__ AH, const __half* __restrict__ GhT,
    const __half* __restrict__ HhT,
    float* __restrict__ Pb, float* __restrict__ Qb)
{
  __shared__ __align__(16) _Float16 Ats[64][72];  // qt staging, pitch 144 B
  const int tid = threadIdx.x;
  const int lane = tid & 63, wv = tid >> 6;
  const int ln = lane & 15, q = lane >> 4;

  if (blockIdx.x < 64) {
    // ---- P part: M=4096 rows of AH, N=320(store 300), K=4096 ----
    const int m0 = blockIdx.x * 64 + wv * 16;
    const __half* Arow = AH + (size_t)(m0 + ln) * 4096;
    for (int nc = 0; nc < 2; nc++) {
      f32x4 acc[10];
#pragma unroll
      for (int j = 0; j < 10; j++) acc[j] = (f32x4){0.f, 0.f, 0.f, 0.f};
      for (int kk = 0; kk < 128; kk++) {
        const f16x8 afr = *(const f16x8*)(Arow + kk * 32 + q * 8);
#pragma unroll
        for (int j = 0; j < 10; j++) {
          const int n = nc * 160 + j * 16 + ln;
          const f16x8 bfr = *(const f16x8*)(GhT + (size_t)n * 4096 + kk * 32 + q * 8);
          acc[j] = __builtin_amdgcn_mfma_f32_16x16x32_f16(afr, bfr, acc[j], 0, 0, 0);
        }
      }
#pragma unroll
      for (int j = 0; j < 10; j++) {
        const int n = nc * 160 + j * 16 + ln;
        if (n < NC) {
#pragma unroll
          for (int r = 0; r < 4; r++)
            Pb[(size_t)(m0 + q * 4 + r) * NC + n] = acc[j][r];
        }
      }
    }
  } else {
    // ---- Q part: Q[j][f] = sum_i a[i][j] H[i][f]; a transposed via LDS ----
    const int j0 = (blockIdx.x - 64) * 64;
    f32x4 acc[20];
#pragma unroll
    for (int j = 0; j < 20; j++) acc[j] = (f32x4){0.f, 0.f, 0.f, 0.f};
    const int il8 = tid >> 2, j8 = (tid & 3) * 16;  // staging role
    for (int ic = 0; ic < 4096; ic += 64) {
      __syncthreads();
      {
        const __half* src = AH + (size_t)(ic + il8) * 4096 + j0 + j8;
        const f16x8 v0 = *(const f16x8*)src;
        const f16x8 v1 = *(const f16x8*)(src + 8);
#pragma unroll
        for (int jj = 0; jj < 8; jj++) Ats[j8 + jj][il8] = v0[jj];
#pragma unroll
        for (int jj = 0; jj < 8; jj++) Ats[j8 + 8 + jj][il8] = v1[jj];
      }
      __syncthreads();
#pragma unroll
      for (int s = 0; s < 2; s++) {
        const f16x8 afr = *(const f16x8*)&Ats[wv * 16 + ln][s * 32 + q * 8];
        const __half* bbase = HhT + ic + s * 32 + q * 8;
#pragma unroll
        for (int j = 0; j < 20; j++) {
          const f16x8 bfr = *(const f16x8*)(bbase + (size_t)(j * 16 + ln) * 4096);
          acc[j] = __builtin_amdgcn_mfma_f32_16x16x32_f16(afr, bfr, acc[j], 0, 0, 0);
        }
      }
    }
#pragma unroll
    for (int j = 0; j < 20; j++) {
      const int f = j * 16 + ln;
      if (f < NC) {
#pragma unroll
        for (int r = 0; r < 4; r++)
          Qb[(size_t)(j0 + wv * 16 + q * 4 + r) * NC + f] = acc[j][r];
      }
    }
  }
}

// ---------------- tail ---------------------------------------------------------
__global__ void reduce_uv(const float* __restrict__ X, const float* __restrict__ Yp,
                          float* __restrict__ inp, int off)
{
  const int j = threadIdx.x;
  if (j >= NC) return;
  const int r0 = blockIdx.x * 128;
  float s = 0.f;
  for (int r = r0; r < r0 + 128; r++)
    s += fmaxf(X[(size_t)r * NC + j], Yp[(size_t)r * NC + j]);
  atomicAdd(&inp[off + j], s);
}

__global__ void fc1_k(const float* __restrict__ w1, const float* __restrict__ b1,
                      const float* __restrict__ inp, float* __restrict__ x)
{
  const int r = blockIdx.x * 256 + threadIdx.x;
  if (r >= 2000) return;
  float s = b1[r];
  const float* wr = w1 + (size_t)r * 600;
  for (int k = 0; k < 600; k++) s += wr[k] * inp[k];
  x[r] = fmaxf(s, 0.f);
}

__global__ void fc2_k(const float* __restrict__ x, const float* __restrict__ w2,
                      const float* __restrict__ b2, float* __restrict__ outp)
{
  const int tid = threadIdx.x;
  float s = 0.f;
  for (int i = tid; i < 2000; i += 256) s += x[i] * w2[i];
#pragma unroll
  for (int off = 32; off > 0; off >>= 1) s += __shfl_down(s, off);
  __shared__ float red[4];
  if ((tid & 63) == 0) red[tid >> 6] = s;
  __syncthreads();
  if (tid == 0) outp[0] = red[0] + red[1] + red[2] + red[3] + b2[0];
}

// ---------------- launch --------------------------------------------------------
extern "C" void kernel_launch(void* const* d_in, const int* in_sizes, int n_in,
                              void* d_out, int out_size, void* d_ws, size_t ws_size,
                              hipStream_t stream)
{
  const float* in_solv  = (const float*)d_in[0];
  const float* in_solu  = (const float*)d_in[1];
  const float* solv_Wih = (const float*)d_in[2];
  const float* solv_Whh = (const float*)d_in[3];
  const float* solv_bih = (const float*)d_in[4];
  const float* solv_bhh = (const float*)d_in[5];
  const float* solu_Wih = (const float*)d_in[6];
  const float* solu_Whh = (const float*)d_in[7];
  const float* solu_bih = (const float*)d_in[8];
  const float* solu_bhh = (const float*)d_in[9];
  const float* fc1_w = (const float*)d_in[10];
  const float* fc1_b = (const float*)d_in[11];
  const float* fc2_w = (const float*)d_in[12];
  const float* fc2_b = (const float*)d_in[13];
  float* outp = (float*)d_out;
  float* ws = (float*)d_ws;

  // ---- workspace layout (float offsets); peak 16,067,200 fl ----
  constexpr size_t off_P   = 0;
  constexpr size_t off_Q   = 1228800;
  constexpr size_t off_inp = 2457600;   // 640
  constexpr size_t off_x   = 2458240;   // 2048
  constexpr size_t off_il  = 2460288;   // 4096
  constexpr size_t off_xg  = 2468480;
  constexpr size_t off_L0  = off_xg + (size_t)4 * 2457600;   // 12,298,880
  constexpr size_t off_HG  = off_L0 + 1310720;               // 13,609,600

  float*  xg   = ws + off_xg;
  float*  Hb   = ws + off_HG;
  float*  Gb   = Hb + 1228800;
  float*  Pb   = ws + off_P;
  float*  Qb   = ws + off_Q;
  float*  inp  = ws + off_inp;
  float*  xf   = ws + off_x;
  float*  il   = ws + off_il;
  __half* Wihh = (__half*)(ws + off_P);
  __half* Avh  = (__half*)(ws + off_L0);
  __half* Auh  = Avh + 4096 * 320;
  __half* L0vh = (__half*)(ws + off_HG);
  __half* L0uh = L0vh + 4096 * 320;
  __half* Hh   = (__half*)(ws + off_L0);   // reuses Avh/Auh space (dead)
  __half* Gh   = Hh + 4096 * 320;
  __half* AH   = (__half*)(ws + off_xg);   // after scans (xg dead)
  __half* HhT  = AH + (size_t)4096 * 4096;
  __half* GhT  = HhT + 320 * 4096;

  // ---- prep: zero L0vh/L0uh pads, convert weights + inputs to fp16 ----
  zero_f<<<5120, 256, 0, stream>>>(ws + off_HG, 1310720);
  conv_w<<<(8 * 640 * 320 + 255) / 256, 256, 0, stream>>>(solv_Wih, solu_Wih, Wihh);
  conv_x<<<5120, 256, 0, stream>>>(in_solv, Avh, 4096);
  conv_x<<<5120, 256, 0, stream>>>(in_solu, Auh, 4096);

  // ---- layer 0 (scan writes fp16 L0vh/L0uh directly; no fp32 out) ----
  xg_mfma<<<dim3(64, 4), 256, 0, stream>>>(Avh, Auh, Wihh,
      solv_bih, solv_bhh, solu_bih, solu_bhh, xg, 0);
  lstm_scan<<<4, 512, 0, stream>>>(solv_Whh, solu_Whh, xg,
      nullptr, nullptr, L0vh, L0uh, 0, 0);

  // ---- layer 1 (scan writes fp32 Hb/Gb + fp16 Hh/Gh) ----
  xg_mfma<<<dim3(64, 4), 256, 0, stream>>>(L0vh, L0uh, Wihh + (size_t)4 * 640 * 320,
      solv_bih, solv_bhh, solu_bih, solu_bhh, xg, 1);
  lstm_scan<<<4, 512, 0, stream>>>(solv_Whh, solu_Whh, xg,
      Hb, Gb, Hh, Gh, 1, 1);

  // ---- attention: S once (fp16), rowsum, scale, P/Q combined ----
  conv_t<<<5120, 256, 0, stream>>>(Hb, HhT);
  conv_t<<<5120, 256, 0, stream>>>(Gb, GhT);
  s_gemm<<<dim3(64, 4), 256, 0, stream>>>(Hh, Gh, AH);
  rowsum_k<<<4096, 256, 0, stream>>>(AH, il);
  scale_k<<<8192, 256, 0, stream>>>(AH, il);
  pq_mfma<<<128, 256, 0, stream>>>(AH, GhT, HhT, Pb, Qb);

  // ---- tail ----
  zero_f<<<3, 256, 0, stream>>>(inp, 640);
  reduce_uv<<<32, 320, 0, stream>>>(Hb, Pb, inp, 0);
  reduce_uv<<<32, 320, 0, stream>>>(Gb, Qb, inp, 300);
  fc1_k<<<8, 256, 0, stream>>>(fc1_w, fc1_b, inp, xf);
  fc2_k<<<1, 256, 0, stream>>>(xf, fc2_w, fc2_b, outp);
}